// Round 7
// baseline (684.357 us; speedup 1.0000x reference)
//
#include <hip/hip_runtime.h>

typedef float f4 __attribute__((ext_vector_type(4)));

// Thread-per-token structure: NO cross-lane reduction in the main loop.
// Block = 256 thr = 4 waves, owns 64 tokens. Wave w: k-half H = w>>1
// (512 k), tokens (w&1)*32..+32. Lane = 2t+h: token t of the wave's set,
// h interleaves 16B granules so lane pairs share 128B lines (32 distinct
// lines per load instr, fully consumed in a 4-instr burst -> MSHR-merge,
// no L1-reuse dependence). W staged fp32 in LDS once per block, read as
// wave-uniform(2-addr) ds_read_b128 broadcasts -> no weight VGPRs.
// acc[9] f4 per lane; end: hadd + shfl_xor(1) pair-combine + tiny LDS
// half-combine + softmax. All fp32 (absmax ~1e-6).

#define TPB 64   // tokens per block

__global__ __launch_bounds__(256)
void moa_split(const float* __restrict__ tok,
               const float* __restrict__ Wq,
               const float* __restrict__ Wk,
               const float* __restrict__ Wv,
               float* __restrict__ out) {
  __shared__ __align__(16) float wlds[9 * 1024];   // 36 KB, [j][k]
  __shared__ float cbuf[2 * 9 * 64];               // 4.6 KB, [H][j][tokInBlk]
  const int tid = threadIdx.x;
  const int T0 = blockIdx.x * TPB;

  // ---- stage W (fp32): 2304 f4s, 9 per thread, coalesced ----
  {
    const float* Wsrc[3] = {Wq, Wk, Wv};
#pragma unroll
    for (int r = 0; r < 9; ++r) {
      const int idx = r * 256 + tid;     // f4 index 0..2303
      const int j   = idx >> 8;          // expert row 0..8
      const int k4  = idx & 255;
      *(f4*)(wlds + j * 1024 + k4 * 4) =
          *(const f4*)(Wsrc[j / 3] + (j % 3) * 1024 + k4 * 4);
    }
  }
  __syncthreads();

  const int wv_    = tid >> 6;               // wave 0..3
  const int lane   = tid & 63;
  const int H      = wv_ >> 1;               // k-half 0/1
  const int t      = lane >> 1;              // token-in-wave 0..31
  const int h      = lane & 1;               // 16B interleave part
  const int tokIdx = (wv_ & 1) * 32 + t;     // token-in-block 0..63

  const float* xp = tok + (size_t)(T0 + tokIdx) * 1024 + H * 512 + h * 4;
  const float* wp = wlds + H * 512 + h * 4;  // j stride 1024 floats

  f4 acc[9];
#pragma unroll
  for (int j = 0; j < 9; ++j) acc[j] = (f4)0.0f;

  // ---- main loop: 8 macro-steps of 64 k (8 f4/lane), double-buffered ----
  f4 xa[8], xb[8];
#pragma unroll
  for (int g = 0; g < 8; ++g) xa[g] = *(const f4*)(xp + g * 8);

#pragma unroll
  for (int s = 0; s < 8; ++s) {
    f4* cur = (s & 1) ? xb : xa;     // compile-time after full unroll
    f4* nxt = (s & 1) ? xa : xb;
    if (s < 7) {
#pragma unroll
      for (int g = 0; g < 8; ++g)
        nxt[g] = *(const f4*)(xp + (s + 1) * 64 + g * 8);
    }
#pragma unroll
    for (int g = 0; g < 8; ++g) {
#pragma unroll
      for (int j = 0; j < 9; ++j) {
        const f4 wvv = *(const f4*)(wp + j * 1024 + s * 64 + g * 8);
        acc[j] += cur[g] * wvv;      // 288 v_fma + 72 broadcast ds_read/step
      }
    }
  }

  // ---- pair combine (1 shfl) + per-half LDS write (conflict-free) ----
#pragma unroll
  for (int j = 0; j < 9; ++j) {
    float v = (acc[j].x + acc[j].y) + (acc[j].z + acc[j].w);
    v += __shfl_xor(v, 1, 64);
    if (h == 0) cbuf[H * 576 + j * 64 + tokIdx] = v;
  }
  __syncthreads();

  // ---- epilogue: 64 threads, one token each; softmax chain; store ----
  if (tid < TPB) {
    float r[9];
#pragma unroll
    for (int j = 0; j < 9; ++j)
      r[j] = cbuf[j * 64 + tid] + cbuf[576 + j * 64 + tid];
    // q=r[0..2], k=r[3..5], v=r[6..8]
    float lg[3];
#pragma unroll
    for (int e = 0; e < 3; ++e) {
      float e0 = __expf(r[e] * r[3]);
      float e1 = __expf(r[e] * r[4]);
      float e2 = __expf(r[e] * r[5]);
      float den = (e0 + e1) + e2;
      float num = e0 * r[6] + e1 * r[7] + e2 * r[8];
      lg[e] = num * __builtin_amdgcn_rcpf(den);
    }
    float u0 = __expf(lg[0]);
    float u1 = __expf(lg[1]);
    float u2 = __expf(lg[2]);
    float rs = __builtin_amdgcn_rcpf((u0 + u1) + u2);
    const size_t T = (size_t)T0 + tid;
    out[T * 3 + 0] = u0 * rs;
    out[T * 3 + 1] = u1 * rs;
    out[T * 3 + 2] = u2 * rs;
  }
}

extern "C" void kernel_launch(void* const* d_in, const int* in_sizes, int n_in,
                              void* d_out, int out_size, void* d_ws, size_t ws_size,
                              hipStream_t stream) {
  const float* tok = (const float*)d_in[0];
  const float* Wq  = (const float*)d_in[1];
  const float* Wk  = (const float*)d_in[2];
  const float* Wv  = (const float*)d_in[3];
  float* out = (float*)d_out;

  const int n_tokens = in_sizes[0] / 1024;   // 32768
  const int blocks   = n_tokens / TPB;       // 512

  hipLaunchKernelGGL(moa_split, dim3(blocks), dim3(256), 0, stream,
                     tok, Wq, Wk, Wv, out);
}

// Round 8
// 27.645 us; speedup vs baseline: 24.7550x; 24.7550x over previous
//
#include <hip/hip_runtime.h>

typedef float f4 __attribute__((ext_vector_type(4)));

// R4 structure + 2-token ILP. One wave per 8 tokens, processed as 4 pairs.
// Lane i owns d-positions {4i + 256c : c=0..3}: global_load_dwordx4, 64
// lanes x 16B = 1KB coalesced per instruction. 9 weight rows resident in
// 144 regs (AGPR-parked on gfx950 unified file; VALU reads AGPR directly).
// Two fully independent per-token chains (FMA -> DPP reduce -> softmax)
// interleave in the issue slots that were dependency stalls in R4.
// NOTE: never raise min-waves in __launch_bounds__ (R3: (256,4) -> weight
// rematerialization, FETCH 66->450MB). No LDS, no barriers.
#define TPW 8

template <int CTRL>
__device__ __forceinline__ float dpp_add(float x) {
  int yi = __builtin_amdgcn_update_dpp(0, __float_as_int(x), CTRL, 0xF, 0xF, true);
  return x + __int_as_float(yi);
}

// After this, lane 63 holds the full 64-lane sum.
__device__ __forceinline__ float wave_sum63(float x) {
  x = dpp_add<0x111>(x);  // row_shr:1
  x = dpp_add<0x112>(x);  // row_shr:2
  x = dpp_add<0x114>(x);  // row_shr:4
  x = dpp_add<0x118>(x);  // row_shr:8
  x = dpp_add<0x142>(x);  // row_bcast:15
  x = dpp_add<0x143>(x);  // row_bcast:31
  return x;
}

__device__ __forceinline__ void softmax3(const float* s9, float& o0, float& o1, float& o2) {
  float lg[3];
#pragma unroll
  for (int e = 0; e < 3; ++e) {
    float e0 = __expf(s9[e] * s9[3]);
    float e1 = __expf(s9[e] * s9[4]);
    float e2 = __expf(s9[e] * s9[5]);
    float den = (e0 + e1) + e2;
    float num = e0 * s9[6] + e1 * s9[7] + e2 * s9[8];
    lg[e] = num * __builtin_amdgcn_rcpf(den);
  }
  float u0 = __expf(lg[0]);
  float u1 = __expf(lg[1]);
  float u2 = __expf(lg[2]);
  float rs = __builtin_amdgcn_rcpf((u0 + u1) + u2);
  o0 = u0 * rs; o1 = u1 * rs; o2 = u2 * rs;
}

__global__ __launch_bounds__(256, 2)
void moa_kernel(const float* __restrict__ tok,
                const float* __restrict__ Wq,
                const float* __restrict__ Wk,
                const float* __restrict__ Wv,
                float* __restrict__ out,
                int n_tokens) {
  const int lane = threadIdx.x & 63;
  const int wid  = (blockIdx.x << 2) | (threadIdx.x >> 6);
  const int base = lane << 2;

  // ---- 9 weight vectors -> regs (coalesced; L2/L3-resident broadcast) ----
  f4 w[9][4];
  const float* Wp[3] = {Wq, Wk, Wv};
#pragma unroll
  for (int m = 0; m < 3; ++m)
#pragma unroll
    for (int e = 0; e < 3; ++e)
#pragma unroll
      for (int c = 0; c < 4; ++c)
        w[m * 3 + e][c] = *(const f4*)(Wp[m] + e * 1024 + c * 256 + base);

  const int t0 = wid * TPW;
  if (t0 >= n_tokens) return;
  const float* wbase = tok + (size_t)t0 * 1024 + base;

  // ---- prologue: load pair 0 ----
  f4 xa[2][4], xb[2][4];
#pragma unroll
  for (int p = 0; p < 2; ++p)
#pragma unroll
    for (int c = 0; c < 4; ++c)
      xa[p][c] = *(const f4*)(wbase + (size_t)p * 1024 + c * 256);

  float outv = 0.0f;

#pragma unroll
  for (int i = 0; i < TPW / 2; ++i) {          // 4 pairs
    f4 (&cur)[2][4] = (i & 1) ? xb : xa;       // compile-time after unroll
    f4 (&nxt)[2][4] = (i & 1) ? xa : xb;

    // issue next pair's 8 loads before any compute
    if (i < TPW / 2 - 1) {
#pragma unroll
      for (int p = 0; p < 2; ++p)
#pragma unroll
        for (int c = 0; c < 4; ++c)
          nxt[p][c] = *(const f4*)(wbase + (size_t)(2 * (i + 1) + p) * 1024 + c * 256);
    }

    // ---- two independent dot blocks ----
    float sA[9], sB[9];
#pragma unroll
    for (int j = 0; j < 9; ++j) {
      f4 a = cur[0][0] * w[j][0];
      a += cur[0][1] * w[j][1];
      a += cur[0][2] * w[j][2];
      a += cur[0][3] * w[j][3];
      sA[j] = (a.x + a.y) + (a.z + a.w);
      f4 b = cur[1][0] * w[j][0];
      b += cur[1][1] * w[j][1];
      b += cur[1][2] * w[j][2];
      b += cur[1][3] * w[j][3];
      sB[j] = (b.x + b.y) + (b.z + b.w);
    }

    // ---- interleaved DPP reductions (independent chains fill stalls) ----
#pragma unroll
    for (int j = 0; j < 9; ++j) {
      sA[j] = wave_sum63(sA[j]);
      sB[j] = wave_sum63(sB[j]);
    }

    // ---- two softmax chains (valid in lane 63) ----
    float a0, a1, a2, b0, b1, b2;
    softmax3(sA, a0, a1, a2);
    softmax3(sB, b0, b1, b2);

    // broadcast lane 63's results
    float rA[3] = {
      __int_as_float(__builtin_amdgcn_readlane(__float_as_int(a0), 63)),
      __int_as_float(__builtin_amdgcn_readlane(__float_as_int(a1), 63)),
      __int_as_float(__builtin_amdgcn_readlane(__float_as_int(a2), 63))};
    float rB[3] = {
      __int_as_float(__builtin_amdgcn_readlane(__float_as_int(b0), 63)),
      __int_as_float(__builtin_amdgcn_readlane(__float_as_int(b1), 63)),
      __int_as_float(__builtin_amdgcn_readlane(__float_as_int(b2), 63))};

    // collect into per-lane output slot (token 2i -> lanes 6i..6i+2, etc.)
#pragma unroll
    for (int c = 0; c < 3; ++c) {
      outv = (lane == 6 * i + c)     ? rA[c] : outv;
      outv = (lane == 6 * i + 3 + c) ? rB[c] : outv;
    }
  }

  // ---- one coalesced 96B store per wave ----
  const int oidx = t0 * 3 + lane;
  if (lane < 3 * TPW) out[oidx] = outv;
}

extern "C" void kernel_launch(void* const* d_in, const int* in_sizes, int n_in,
                              void* d_out, int out_size, void* d_ws, size_t ws_size,
                              hipStream_t stream) {
  const float* tok = (const float*)d_in[0];
  const float* Wq  = (const float*)d_in[1];
  const float* Wk  = (const float*)d_in[2];
  const float* Wv  = (const float*)d_in[3];
  float* out = (float*)d_out;

  const int n_tokens = in_sizes[0] / 1024;           // 32768
  const int waves    = (n_tokens + TPW - 1) / TPW;   // 4096
  const int blocks   = (waves + 3) / 4;              // 1024

  hipLaunchKernelGGL(moa_kernel, dim3(blocks), dim3(256), 0, stream,
                     tok, Wq, Wk, Wv, out, n_tokens);
}